// Round 7
// baseline (4135.729 us; speedup 1.0000x reference)
//
#include <hip/hip_runtime.h>

typedef unsigned short ushort_t;
typedef unsigned int   uint_t;
typedef unsigned long long u64;
typedef __attribute__((ext_vector_type(8))) short  bf16x8;
typedef __attribute__((ext_vector_type(4))) float  f32x4;

#define B_      32
#define TIN_    128
#define TOUT_   500
#define R_      5
#define STEPS_  100
#define MEL_    128
#define SPEC_   513
#define NWG_    32

// ---------------- ws layout (bytes) ----------------
// zeroed each launch:
#define ZB_SLOTS   0          // 32*32 int (128B stride per WG)
#define ZB_AH      8192       // [32][256] bf16  h_att
#define ZB_ARH     24576      // [32][256] bf16  r*h_att
#define ZB_AHC     40960      // [32][512] bf16  [h_att | ctx]
#define ZB_AXH1    73728      // [32][512] bf16  [aco | h1]
#define ZB_AXRH1   106496     // [32][512] bf16  [aco | r*h1]
#define ZB_AY1H2   139264     // [32][512] bf16  [y1 | h2]
#define ZB_AY1RH2  172032     // [32][512] bf16  [y1 | r*h2]
#define ZB_UBUF    221184     // [32][256] f32   u gates att
#define ZB_U1BUF   253952     // [32][256] f32
#define ZB_U2BUF   286720     // [32][256] f32
#define ZB_QSBUF   335872     // [32][2] f32 (padded)
#define ZB_END     435200
// written by prep kernels:
#define OFF_ACOSPK2 505856    // 32*256 f32
#define OFF_MS2     538624    // 20 f32
#define OFF_KS2     539136    // 20 f32
#define OFF_SPK2    501760    // 32*32 f32
#define OFF_PREG2   539648    // 100*32*512 f32
#define OFF_PREC2   7093248   // 100*32*256 f32
#define OFF_Y2G     10370048  // 100*32*256 f32
#define OFF_KEYSP   13646848  // [32 b][128 t][256] bf16 (plain)
#define OFF_ENCP    15744000  // [32 b][128 t][256] bf16 (plain)
#define OFF_WQB     17841152  // [256][256] bf16
// end 17,972,224

// ---------------- helpers ----------------
__device__ __forceinline__ float bf1(ushort_t u){ return __uint_as_float(((uint_t)u) << 16); }
__device__ __forceinline__ ushort_t f2bf(float f){
    uint_t b = __float_as_uint(f);
    uint_t r = (b + 0x7fffu + ((b >> 16) & 1u)) >> 16;
    return (ushort_t)r;
}
__device__ __forceinline__ float fexp2(float x){ return __builtin_amdgcn_exp2f(x); }
__device__ __forceinline__ float frcp(float x){ return __builtin_amdgcn_rcpf(x); }
__device__ __forceinline__ float sigm_f(float x){ return frcp(1.f + fexp2(-1.44269504f * x)); }
__device__ __forceinline__ float tanh_f(float x){
    float e = fexp2(2.88539008f * x);
    return 1.f - 2.f * frcp(e + 1.f);
}
// LLC-coherent relaxed agent atomics for data exchange.
__device__ __forceinline__ u64 ld8(const void* p){
    return __hip_atomic_load((const u64*)p, __ATOMIC_RELAXED, __HIP_MEMORY_SCOPE_AGENT);
}
__device__ __forceinline__ void st8(void* p, u64 v){
    __hip_atomic_store((u64*)p, v, __ATOMIC_RELAXED, __HIP_MEMORY_SCOPE_AGENT);
}
__device__ __forceinline__ float ld4f(const void* p){
    uint_t u = __hip_atomic_load((const uint_t*)p, __ATOMIC_RELAXED, __HIP_MEMORY_SCOPE_AGENT);
    return __uint_as_float(u);
}
__device__ __forceinline__ float u64lo(u64 v){ return __uint_as_float((uint_t)v); }
__device__ __forceinline__ float u64hi(u64 v){ return __uint_as_float((uint_t)(v >> 32)); }
// Same-type LDS reads packed in registers (no u64 punning of ushort/float LDS).
__device__ __forceinline__ u64 pack4(const ushort_t* q){
    return (u64)q[0] | ((u64)q[1] << 16) | ((u64)q[2] << 32) | ((u64)q[3] << 48);
}
__device__ __forceinline__ u64 pack2f(const float* f){
    return (u64)__float_as_uint(f[0]) | ((u64)__float_as_uint(f[1]) << 32);
}
#define CBAR() asm volatile("" ::: "memory")

// ---------------- K1: tiny constants ----------------
__global__ __launch_bounds__(256) void k_small(
    const float* __restrict__ st, const float* __restrict__ Ws_pre,
    const float* __restrict__ bs_pre, const float* __restrict__ Wk_s,
    const float* __restrict__ spk_embed, const int* __restrict__ speaker,
    const float* __restrict__ Wa, const float* __restrict__ ba,
    float* __restrict__ spk_sel, float* __restrict__ aco_spk,
    float* __restrict__ ms_g, float* __restrict__ ks_g)
{
    __shared__ float spk_l[B_*32];
    __shared__ float ms_l[20];
    const int tid = threadIdx.x;
    for(int i=tid; i<B_*32; i+=256){
        int b = i >> 5, j = i & 31;
        float v = spk_embed[speaker[b]*32 + j];
        spk_l[i] = v; spk_sel[i] = v;
    }
    if(tid < 20){
        int n = tid >> 1, j = tid & 1;
        float v = st[n*2]*Ws_pre[j] + st[n*2+1]*Ws_pre[2+j] + bs_pre[j];
        v = fmaxf(v, 0.f);
        ms_l[tid] = v; ms_g[tid] = v;
    }
    __syncthreads();
    if(tid < 20){
        int n = tid >> 1, j = tid & 1;
        ks_g[tid] = ms_l[n*2]*Wk_s[j] + ms_l[n*2+1]*Wk_s[2+j];
    }
    for(int i=tid; i<B_*256; i+=256){
        int b = i >> 8, n = i & 255;
        float acc = ba[n];
        #pragma unroll
        for(int k=0;k<32;++k) acc = fmaf(spk_l[b*32+k], Wa[(256+k)*256 + n], acc);
        aco_spk[i] = acc;
    }
}

// ---------------- K4: keys = enc @ Wk -> bf16 plain [b][t][256] ----------------
__global__ __launch_bounds__(256) void k_keys(const float* __restrict__ enc,
                                              const float* __restrict__ Wk,
                                              ushort_t* __restrict__ keysb){
    __shared__ float x16[16][256];
    const int bid = blockIdx.x;      // 256 = 32 b * 8 tgroups
    const int b = bid >> 3, tg = bid & 7, t0 = tg*16;
    const int tid = threadIdx.x;
    for(int i=tid; i<16*256; i+=256){
        int r = i >> 8, k = i & 255;
        x16[r][k] = enc[((size_t)b*TIN_ + t0 + r)*256 + k];
    }
    __syncthreads();
    float acc[16];
    #pragma unroll
    for(int r=0;r<16;++r) acc[r] = 0.f;
    for(int k=0;k<256;++k){
        float w = Wk[k*256 + tid];
        #pragma unroll
        for(int r=0;r<16;++r) acc[r] = fmaf(x16[r][k], w, acc[r]);
    }
    #pragma unroll
    for(int r=0;r<16;++r)
        keysb[((size_t)b*TIN_ + t0 + r)*256 + tid] = f2bf(acc[r]);
}

// ---------------- converters ----------------
__global__ __launch_bounds__(256) void k_cvt_enc(const float* __restrict__ enc,
                                                 ushort_t* __restrict__ encb){
    int o = blockIdx.x*256 + threadIdx.x;      // 4096 blocks
    encb[o] = f2bf(enc[o]);
}
__global__ __launch_bounds__(256) void k_cvt_wq(const float* __restrict__ Wq,
                                                ushort_t* __restrict__ wqb){
    int o = blockIdx.x*256 + threadIdx.x;      // 256 blocks
    wqb[o] = f2bf(Wq[o]);
}

// ---------------- K3: prenet + x-part of att-GRU for all steps ----------------
__global__ __launch_bounds__(256) void k_prenet(
    const float* __restrict__ mg, const float* __restrict__ spk_sel,
    const float* __restrict__ Wp1, const float* __restrict__ bp1,
    const float* __restrict__ Wp2, const float* __restrict__ bp2,
    const float* __restrict__ Wg_att, const float* __restrict__ bg_att,
    const float* __restrict__ Wc_att, const float* __restrict__ bc_att,
    float* __restrict__ preg, float* __restrict__ prec)
{
    __shared__ float fr[16][128];
    __shared__ float p1[16][256];
    __shared__ float p2[16][128];
    __shared__ float spk_l[16][32];
    const int r0 = blockIdx.x * 16;
    const int tid = threadIdx.x;
    for(int i=tid; i<16*128; i+=256){
        int r = i >> 7, mcol = i & 127;
        int row = r0 + r, s = row >> 5, b = row & 31;
        fr[r][mcol] = (s == 0) ? 0.f : mg[((size_t)b*TOUT_ + s*R_ - 1)*MEL_ + mcol];
    }
    for(int i=tid; i<16*32; i+=256){
        int r = i >> 5, j = i & 31;
        spk_l[r][j] = spk_sel[((r0 + r) & 31)*32 + j];
    }
    __syncthreads();
    {
        float acc[16];
        #pragma unroll
        for(int r=0;r<16;++r) acc[r]=0.f;
        for(int k=0;k<128;++k){
            float w = Wp1[k*256 + tid];
            #pragma unroll
            for(int r=0;r<16;++r) acc[r] = fmaf(fr[r][k], w, acc[r]);
        }
        float bb = bp1[tid];
        #pragma unroll
        for(int r=0;r<16;++r) p1[r][tid] = fmaxf(acc[r] + bb, 0.f);
    }
    __syncthreads();
    if(tid < 128){
        float acc[16];
        #pragma unroll
        for(int r=0;r<16;++r) acc[r]=0.f;
        for(int k=0;k<256;++k){
            float w = Wp2[k*128 + tid];
            #pragma unroll
            for(int r=0;r<16;++r) acc[r] = fmaf(p1[r][k], w, acc[r]);
        }
        float bb = bp2[tid];
        #pragma unroll
        for(int r=0;r<16;++r) p2[r][tid] = fmaxf(acc[r] + bb, 0.f);
    }
    __syncthreads();
    {
        float aA[16], aB[16];
        #pragma unroll
        for(int r=0;r<16;++r){ aA[r]=0.f; aB[r]=0.f; }
        for(int k=0;k<128;++k){
            float wA = Wg_att[k*512 + tid], wB = Wg_att[k*512 + tid + 256];
            #pragma unroll
            for(int r=0;r<16;++r){ float pv = p2[r][k]; aA[r]=fmaf(pv,wA,aA[r]); aB[r]=fmaf(pv,wB,aB[r]); }
        }
        for(int k=0;k<32;++k){
            float wA = Wg_att[(128+k)*512 + tid], wB = Wg_att[(128+k)*512 + tid + 256];
            #pragma unroll
            for(int r=0;r<16;++r){ float sv = spk_l[r][k]; aA[r]=fmaf(sv,wA,aA[r]); aB[r]=fmaf(sv,wB,aB[r]); }
        }
        float bA = bg_att[tid], bB = bg_att[tid + 256];
        #pragma unroll
        for(int r=0;r<16;++r){
            preg[(size_t)(r0+r)*512 + tid]       = aA[r] + bA;
            preg[(size_t)(r0+r)*512 + tid + 256] = aB[r] + bB;
        }
    }
    {
        float acc[16];
        #pragma unroll
        for(int r=0;r<16;++r) acc[r]=0.f;
        for(int k=0;k<128;++k){
            float w = Wc_att[k*256 + tid];
            #pragma unroll
            for(int r=0;r<16;++r) acc[r] = fmaf(p2[r][k], w, acc[r]);
        }
        for(int k=0;k<32;++k){
            float w = Wc_att[(128+k)*256 + tid];
            #pragma unroll
            for(int r=0;r<16;++r) acc[r] = fmaf(spk_l[r][k], w, acc[r]);
        }
        float bb = bc_att[tid];
        #pragma unroll
        for(int r=0;r<16;++r) prec[(size_t)(r0+r)*256 + tid] = acc[r] + bb;
    }
}

// ---------------- cooperative scan helpers ----------------
// STRONG barrier (r3-proven): vmcnt drain, RELEASE flag store (wbl2), RELAXED
// polls (no per-poll invalidate!), then ONE acquire fence (one buffer_inv).
__device__ __forceinline__ void gridbar(int* slots, int p, int seq, int tid){
    asm volatile("s_waitcnt vmcnt(0)" ::: "memory");
    __syncthreads();
    if(tid == 0)
        __hip_atomic_store(&slots[p*32], seq, __ATOMIC_RELEASE, __HIP_MEMORY_SCOPE_AGENT);
    if(tid < NWG_){
        while(__hip_atomic_load(&slots[tid*32], __ATOMIC_RELAXED, __HIP_MEMORY_SCOPE_AGENT) < seq)
            __builtin_amdgcn_s_sleep(1);
        __builtin_amdgcn_fence(__ATOMIC_ACQUIRE, "agent");
    }
    __syncthreads();
}

__device__ __forceinline__ void loadW(const float* W, int ldw, int rowbase, int nk, int kbase,
                                      int Ktot, int col0, int ncols, ushort_t* lds, int tid){
    for(int e = tid; e < 16*nk; e += 512){
        int col = e & 15, k = e >> 4;
        ushort_t v = 0;
        if(col < ncols) v = f2bf(W[(size_t)(rowbase + k)*ldw + col0 + col]);
        lds[(col*Ktot + kbase + k) ^ ((col & 7) << 3)] = v;
    }
}

template<int K>
__device__ __forceinline__ f32x4 do_gemm(const ushort_t* Ab, const ushort_t* Wl, float* red,
                                         int m, int kq, int lane){
    const int row = m*16 + (lane & 15);
    const int col = lane & 15;
    const int ko  = (lane >> 4) * 8;
    u64 av[K/64];
    #pragma unroll
    for(int t = 0; t < K/128; ++t){
        const int k0 = kq*(K/4) + t*32 + ko;
        av[2*t]   = ld8(Ab + row*K + k0);
        av[2*t+1] = ld8(Ab + row*K + k0 + 4);
    }
    f32x4 acc = {0.f,0.f,0.f,0.f};
    #pragma unroll
    for(int t = 0; t < K/128; ++t){
        const int k0 = kq*(K/4) + t*32 + ko;
        union { u64 q[2]; bf16x8 v; } ua;
        ua.q[0] = av[2*t]; ua.q[1] = av[2*t+1];
        bf16x8 b = *reinterpret_cast<const bf16x8*>(Wl + ((col*K + k0) ^ ((col & 7) << 3)));
        acc = __builtin_amdgcn_mfma_f32_16x16x32_bf16(ua.v, b, acc, 0, 0, 0);
    }
    if(kq > 0) *reinterpret_cast<f32x4*>(red + ((kq-1)*2 + m)*256 + lane*4) = acc;
    __syncthreads();
    if(kq == 0){
        #pragma unroll
        for(int j = 0; j < 3; ++j)
            acc += *reinterpret_cast<const f32x4*>(red + (j*2 + m)*256 + lane*4);
    }
    return acc;
}

// ---------------- K5: the cooperative scan ----------------
__global__ __launch_bounds__(512) void k_scan_coop(
    char* ws,
    const float* __restrict__ Wg_att, const float* __restrict__ Wc_att,
    const float* __restrict__ Wq_s,
    const float* __restrict__ v_att, const float* __restrict__ v_s,
    const float* __restrict__ Wa,
    const float* __restrict__ Wg1, const float* __restrict__ Wc1,
    const float* __restrict__ Wg2, const float* __restrict__ Wc2,
    const float* __restrict__ bg1, const float* __restrict__ bc1,
    const float* __restrict__ bg2, const float* __restrict__ bc2,
    const int* __restrict__ inp_mask, float* __restrict__ out_alpha)
{
    const int p = blockIdx.x, tid = threadIdx.x;
    const int lane = tid & 63, wv = tid >> 6;
    const int m = wv & 1, kq = wv >> 1;

    int* slots       = (int*)(ws + ZB_SLOTS);
    ushort_t* A_h    = (ushort_t*)(ws + ZB_AH);
    ushort_t* A_rh   = (ushort_t*)(ws + ZB_ARH);
    ushort_t* A_hc   = (ushort_t*)(ws + ZB_AHC);
    ushort_t* A_xh1  = (ushort_t*)(ws + ZB_AXH1);
    ushort_t* A_xrh1 = (ushort_t*)(ws + ZB_AXRH1);
    ushort_t* A_y1h2 = (ushort_t*)(ws + ZB_AY1H2);
    ushort_t* A_y1rh2= (ushort_t*)(ws + ZB_AY1RH2);
    float* ubuf  = (float*)(ws + ZB_UBUF);
    float* u1buf = (float*)(ws + ZB_U1BUF);
    float* u2buf = (float*)(ws + ZB_U2BUF);
    float* qsbuf = (float*)(ws + ZB_QSBUF);
    const float* acospk = (const float*)(ws + OFF_ACOSPK2);
    const float* msg    = (const float*)(ws + OFF_MS2);
    const float* ksg    = (const float*)(ws + OFF_KS2);
    const float* preg   = (const float*)(ws + OFF_PREG2);
    const float* prec   = (const float*)(ws + OFF_PREC2);
    float* y2g          = (float*)(ws + OFF_Y2G);
    const ushort_t* keysb = (const ushort_t*)(ws + OFF_KEYSP);
    const ushort_t* encb  = (const ushort_t*)(ws + OFF_ENCP);
    const ushort_t* wqb   = (const ushort_t*)(ws + OFF_WQB);

    // LDS: resident weight slices (col-major [16][K], bf16, swizzled)
    __shared__ ushort_t wA[16*256], wB[16*256];
    __shared__ ushort_t wG[16*512], wH[16*512], wI[16*512], wJ[16*512], wK[16*512];
    __shared__ __align__(16) char uni[16384];  // red/CDE scratch | stg(@8K) | stgf(@10K)
    float* red = (float*)uni;
    float* uf  = (float*)uni;
    ushort_t* stg  = (ushort_t*)(uni + 8192);   // bf16 pack tile
    float*    stgf = (float*)(uni + 10240);     // f32 pack tile
    __shared__ float vatt_l[256];
    __shared__ float msks[48];
    __shared__ float ctxs_l[64];
    __shared__ float acosl[256], acofl[256], y1fl[256];
    __shared__ float hfl[256], h1fl[256], h2fl[256];
    __shared__ float bg1s[16], bc1s[8], bg2s[16], bc2s[8], wasl[16];
    __shared__ float wqs_l[512];

    loadW(Wg_att, 512, 160, 256, 0, 256, p*16, 16, wA, tid);
    loadW(Wc_att, 256, 160, 256, 0, 256, p*8,  8,  wB, tid);
    loadW(Wa,     256, 0,   256, 0,   512, p*8, 8, wG, tid);   // rows 0..255  (h)
    loadW(Wa,     256, 288, 256, 256, 512, p*8, 8, wG, tid);   // rows 288..543 (ctx)
    loadW(Wg1,    512, 0,   512, 0, 512, p*16, 16, wH, tid);
    loadW(Wc1,    256, 0,   512, 0, 512, p*8,  8,  wI, tid);
    loadW(Wg2,    512, 0,   512, 0, 512, p*16, 16, wJ, tid);
    loadW(Wc2,    256, 0,   512, 0, 512, p*8,  8,  wK, tid);
    if(tid < 256){
        vatt_l[tid] = v_att[tid];
        acosl[tid]  = acospk[(tid>>3)*256 + p*8 + (tid&7)];
        hfl[tid] = 0.f; h1fl[tid] = 0.f; h2fl[tid] = 0.f;
    }
    wqs_l[tid] = Wq_s[tid];
    if(tid < 20) msks[tid] = msg[tid];
    if(tid >= 20 && tid < 40) msks[tid] = ksg[tid-20];
    if(tid == 40) msks[40] = v_s[0];
    if(tid == 41) msks[41] = v_s[1];
    if(tid < 16){ bg1s[tid] = bg1[p*16+tid]; bg2s[tid] = bg2[p*16+tid]; }
    if(tid < 8){ bc1s[tid] = bc1[p*8+tid]; bc2s[tid] = bc2[p*8+tid]; }
    if(tid < 16) wasl[tid] = Wa[(size_t)(544 + (tid & 1))*256 + p*8 + (tid >> 1)];
    const int maskp = inp_mask[p];
    __syncthreads();

    int seq = 0;
    for(int s = 0; s < STEPS_; ++s){
        const int sb = s*32;
        const int col = lane & 15;
        const int bbase = m*16 + ((lane>>4)<<2);
        // ---- A: att-GRU gates ----
        __syncthreads();   // red WAR guard vs stage K
        u64 hpre[4];
        if(kq == 0 && p < 16){
            #pragma unroll
            for(int r=0;r<4;++r) hpre[r] = ld8(A_h + (bbase+r)*256 + ((p*16+col) & ~3));
        }
        f32x4 acc = do_gemm<256>(A_h, wA, red, m, kq, lane);
        if(kq == 0){
            const int gcol = p*16 + col;
            if(p < 16){
                #pragma unroll
                for(int r=0;r<4;++r){
                    int b = bbase + r;
                    float g = sigm_f(acc[r] + preg[(size_t)(sb + b)*512 + gcol]);
                    float hb = bf1((ushort_t)(hpre[r] >> ((col & 3)*16)));
                    stg[b*16 + col] = f2bf(g * hb);
                }
                CBAR();
                int c = lane, row2 = m*16 + (c>>2), cg = c & 3;
                st8(A_rh + row2*256 + p*16 + cg*4, pack4(stg + row2*16 + cg*4));
            } else {
                #pragma unroll
                for(int r=0;r<4;++r){
                    int b = bbase + r;
                    stgf[b*16 + col] = sigm_f(acc[r] + preg[(size_t)(sb + b)*512 + gcol]);
                }
                CBAR();
                #pragma unroll
                for(int j=0;j<2;++j){
                    int c = lane*2 + j, row2 = m*16 + (c>>3), cg = c & 7;
                    st8(ubuf + row2*256 + (p-16)*16 + cg*2, pack2f(stgf + row2*16 + cg*2));
                }
            }
        }
        gridbar(slots, p, ++seq, tid);   // b1
        // ---- B: att-GRU candidate + h update ----
        float upre[4];
        if(kq == 0 && col < 8){
            #pragma unroll
            for(int r=0;r<4;++r) upre[r] = ld4f(ubuf + (bbase+r)*256 + p*8 + col);
        }
        acc = do_gemm<256>(A_rh, wB, red, m, kq, lane);
        if(kq == 0){
            if(col < 8){
                const int gcol = p*8 + col;
                #pragma unroll
                for(int r=0;r<4;++r){
                    int b = bbase + r;
                    float cc = tanh_f(acc[r] + prec[(size_t)(sb + b)*256 + gcol]);
                    float u  = upre[r];
                    float hn = u*hfl[b*8 + col] + (1.f - u)*cc;
                    hfl[b*8 + col] = hn;
                    stg[b*8 + col] = f2bf(hn);
                }
            }
            CBAR();
            if(lane < 32){
                int c = lane, row2 = m*16 + (c>>1), cg = c & 1;
                u64 v = pack4(stg + row2*8 + cg*4);
                st8(A_h  + row2*256 + p*8 + cg*4, v);
                st8(A_hc + row2*512 + p*8 + cg*4, v);
            }
        }
        gridbar(slots, p, ++seq, tid);   // b2
        // ---- CDE: row-split attention for row p (no cross-WG exchange) ----
        {
            float* hrow   = uf;            // [256]
            float* qpart  = uf + 256;      // [512]
            float* qrow   = uf + 768;      // [256]
            float* escore = uf + 1024;     // [128]
            float* alphaA = uf + 1152;     // [128]
            float* smv    = uf + 1280;     // [1]
            float* cpart  = uf + 1536;     // [512]
            if(tid < 64){
                u64 h4 = ld8(A_h + p*256 + tid*4);
                #pragma unroll
                for(int j=0;j<4;++j) hrow[tid*4+j] = bf1((ushort_t)(h4 >> (j*16)));
            }
            __syncthreads();
            {   // qW partial GEMV: stream wqb (L2/LLC)
                int colq = tid & 255, kh = tid >> 8;
                const ushort_t* wq = wqb + (size_t)(kh*128)*256 + colq;
                float accq = 0.f;
                #pragma unroll 4
                for(int k=0;k<128;++k) accq = fmaf(hrow[kh*128 + k], bf1(wq[(size_t)k*256]), accq);
                qpart[kh*256 + colq] = accq;
            }
            // style query + style context (lanes 0..15 of wave 0)
            if(tid < 16){
                float q0s=0.f, q1s=0.f;
                #pragma unroll
                for(int kk=0;kk<16;++kk){
                    int k = tid*16 + kk; float hv = hrow[k];
                    q0s = fmaf(hv, wqs_l[k*2],   q0s);
                    q1s = fmaf(hv, wqs_l[k*2+1], q1s);
                }
                #pragma unroll
                for(int d=1; d<16; d<<=1){ q0s += __shfl_xor(q0s,d,64); q1s += __shfl_xor(q1s,d,64); }
                if(tid == 0){
                    float es[10]; float mx = -1e30f;
                    #pragma unroll
                    for(int n=0;n<10;++n){
                        float t = msks[40]*tanh_f(msks[20+n*2] + q0s) + msks[41]*tanh_f(msks[20+n*2+1] + q1s);
                        es[n] = t; mx = fmaxf(mx, t);
                    }
                    float sum = 0.f;
                    #pragma unroll
                    for(int n=0;n<10;++n){ float pe = fexp2((es[n]-mx)*1.44269504f); es[n]=pe; sum += pe; }
                    float inv = frcp(sum); float c0=0.f, c1=0.f;
                    #pragma unroll
                    for(int n=0;n<10;++n){ float al = es[n]*inv; c0 = fmaf(al, msks[n*2], c0); c1 = fmaf(al, msks[n*2+1], c1); }
                    float pr2[2] = {c0, c1};
                    st8(qsbuf + p*2, pack2f(pr2));
                }
            }
            __syncthreads();
            if(tid < 256) qrow[tid] = qpart[tid] + qpart[256+tid];
            __syncthreads();
            {   // scores: t = tid>>2 (128), q = tid&3 (64-a chunk)
                int t = tid >> 2, q = tid & 3;
                const ushort_t* kp = keysb + ((size_t)(p*TIN_ + t))*256 + q*64;
                float e = 0.f;
                #pragma unroll
                for(int i2=0;i2<8;++i2){
                    bf16x8 kv = *(const bf16x8*)(kp + i2*8);
                    #pragma unroll
                    for(int j=0;j<8;++j){
                        int a = q*64 + i2*8 + j;
                        e = fmaf(vatt_l[a], tanh_f(bf1((ushort_t)kv[j]) + qrow[a]), e);
                    }
                }
                e += __shfl_xor(e,1,64); e += __shfl_xor(e,2,64);
                if(q == 0) escore[t] = (t < maskp) ? e : -1e9f;
            }
            __syncthreads();
            if(tid < 64){
                float e0 = escore[tid], e1 = escore[tid+64];
                float mx = fmaxf(e0, e1);
                #pragma unroll
                for(int d=1; d<64; d<<=1) mx = fmaxf(mx, __shfl_xor(mx,d,64));
                float a0 = fexp2((e0-mx)*1.44269504f);
                float a1 = fexp2((e1-mx)*1.44269504f);
                alphaA[tid] = a0; alphaA[tid+64] = a1;
                float ssum = a0 + a1;
                #pragma unroll
                for(int d=1; d<64; d<<=1) ssum += __shfl_xor(ssum,d,64);
                if(tid == 0) smv[0] = frcp(ssum);
            }
            __syncthreads();
            if(tid < 128){
                float a = alphaA[tid] * smv[0];
                alphaA[tid] = a;
                out_alpha[((size_t)p*STEPS_ + s)*TIN_ + tid] = a;
            }
            __syncthreads();
            {   // context partial: col = tid&255, th = tid>>8 sums 64 t
                int colq = tid & 255, th = tid >> 8;
                const ushort_t* ep = encb + ((size_t)(p*TIN_ + th*64))*256 + colq;
                float c = 0.f;
                #pragma unroll 4
                for(int tt=0; tt<64; ++tt) c = fmaf(alphaA[th*64+tt], bf1(ep[(size_t)tt*256]), c);
                cpart[th*256 + colq] = c;
            }
            __syncthreads();
            if(tid < 256) stg[tid] = f2bf(cpart[tid] + cpart[256+tid]);
            CBAR();
            __syncthreads();
            if(tid < 64) st8(A_hc + p*512 + 256 + tid*4, pack4(stg + tid*4));
        }
        gridbar(slots, p, ++seq, tid);   // b3
        // ---- G: aco = [h|ctx]@Wa + acospk + ctx_s@Wa_s ----
        if(tid < 32){
            u64 qq = ld8(qsbuf + tid*2);
            ctxs_l[tid*2] = u64lo(qq); ctxs_l[tid*2+1] = u64hi(qq);
        }
        acc = do_gemm<512>(A_hc, wG, red, m, kq, lane);
        if(kq == 0){
            if(col < 8){
                #pragma unroll
                for(int r=0;r<4;++r){
                    int b = bbase + r;
                    float v = acc[r] + acosl[b*8 + col]
                            + ctxs_l[b*2]   * wasl[col*2]
                            + ctxs_l[b*2+1] * wasl[col*2+1];
                    acofl[b*8 + col] = v;
                    stg[b*8 + col] = f2bf(v);
                }
            }
            CBAR();
            if(lane < 32){
                int c = lane, row2 = m*16 + (c>>1), cg = c & 1;
                u64 v = pack4(stg + row2*8 + cg*4);
                st8(A_xh1  + row2*512 + p*8 + cg*4, v);
                st8(A_xrh1 + row2*512 + p*8 + cg*4, v);
            }
        }
        gridbar(slots, p, ++seq, tid);   // b4
        // ---- H: GRU1 gates ----
        if(kq == 0 && p < 16){
            #pragma unroll
            for(int r=0;r<4;++r) hpre[r] = ld8(A_xh1 + (bbase+r)*512 + 256 + ((p*16+col) & ~3));
        }
        acc = do_gemm<512>(A_xh1, wH, red, m, kq, lane);
        if(kq == 0){
            if(p < 16){
                #pragma unroll
                for(int r=0;r<4;++r){
                    int b = bbase + r;
                    float g = sigm_f(acc[r] + bg1s[col]);
                    float hb = bf1((ushort_t)(hpre[r] >> ((col & 3)*16)));
                    stg[b*16 + col] = f2bf(g * hb);
                }
                CBAR();
                int c = lane, row2 = m*16 + (c>>2), cg = c & 3;
                st8(A_xrh1 + row2*512 + 256 + p*16 + cg*4, pack4(stg + row2*16 + cg*4));
            } else {
                #pragma unroll
                for(int r=0;r<4;++r)
                    stgf[(bbase+r)*16 + col] = sigm_f(acc[r] + bg1s[col]);
                CBAR();
                #pragma unroll
                for(int j=0;j<2;++j){
                    int c = lane*2 + j, row2 = m*16 + (c>>3), cg = c & 7;
                    st8(u1buf + row2*256 + (p-16)*16 + cg*2, pack2f(stgf + row2*16 + cg*2));
                }
            }
        }
        gridbar(slots, p, ++seq, tid);   // b5
        // ---- I: GRU1 candidate + y1 ----
        if(kq == 0 && col < 8){
            #pragma unroll
            for(int r=0;r<4;++r) upre[r] = ld4f(u1buf + (bbase+r)*256 + p*8 + col);
        }
        acc = do_gemm<512>(A_xrh1, wI, red, m, kq, lane);
        if(kq == 0){
            if(col < 8){
                #pragma unroll
                for(int r=0;r<4;++r){
                    int b = bbase + r;
                    float cc = tanh_f(acc[r] + bc1s[col]);
                    float u  = upre[r];
                    float hn = u*h1fl[b*8 + col] + (1.f - u)*cc;
                    h1fl[b*8 + col] = hn;
                    stg[b*8 + col] = f2bf(hn);
                    float y1 = hn + acofl[b*8 + col];
                    y1fl[b*8 + col] = y1;
                    stg[256 + b*8 + col] = f2bf(y1);
                }
            }
            CBAR();
            if(lane < 32){
                int c = lane, row2 = m*16 + (c>>1), cg = c & 1;
                u64 vh = pack4(stg + row2*8 + cg*4);
                u64 vy = pack4(stg + 256 + row2*8 + cg*4);
                st8(A_xh1   + row2*512 + 256 + p*8 + cg*4, vh);
                st8(A_y1h2  + row2*512 + p*8 + cg*4, vy);
                st8(A_y1rh2 + row2*512 + p*8 + cg*4, vy);
            }
        }
        gridbar(slots, p, ++seq, tid);   // b6
        // ---- J: GRU2 gates ----
        if(kq == 0 && p < 16){
            #pragma unroll
            for(int r=0;r<4;++r) hpre[r] = ld8(A_y1h2 + (bbase+r)*512 + 256 + ((p*16+col) & ~3));
        }
        acc = do_gemm<512>(A_y1h2, wJ, red, m, kq, lane);
        if(kq == 0){
            if(p < 16){
                #pragma unroll
                for(int r=0;r<4;++r){
                    int b = bbase + r;
                    float g = sigm_f(acc[r] + bg2s[col]);
                    float hb = bf1((ushort_t)(hpre[r] >> ((col & 3)*16)));
                    stg[b*16 + col] = f2bf(g * hb);
                }
                CBAR();
                int c = lane, row2 = m*16 + (c>>2), cg = c & 3;
                st8(A_y1rh2 + row2*512 + 256 + p*16 + cg*4, pack4(stg + row2*16 + cg*4));
            } else {
                #pragma unroll
                for(int r=0;r<4;++r)
                    stgf[(bbase+r)*16 + col] = sigm_f(acc[r] + bg2s[col]);
                CBAR();
                #pragma unroll
                for(int j=0;j<2;++j){
                    int c = lane*2 + j, row2 = m*16 + (c>>3), cg = c & 7;
                    st8(u2buf + row2*256 + (p-16)*16 + cg*2, pack2f(stgf + row2*16 + cg*2));
                }
            }
        }
        gridbar(slots, p, ++seq, tid);   // b7
        // ---- K: GRU2 candidate + y2 (no barrier; loop-top syncthreads guards red) ----
        if(kq == 0 && col < 8){
            #pragma unroll
            for(int r=0;r<4;++r) upre[r] = ld4f(u2buf + (bbase+r)*256 + p*8 + col);
        }
        acc = do_gemm<512>(A_y1rh2, wK, red, m, kq, lane);
        if(kq == 0){
            if(col < 8){
                const int gcol = p*8 + col;
                #pragma unroll
                for(int r=0;r<4;++r){
                    int b = bbase + r;
                    float cc = tanh_f(acc[r] + bc2s[col]);
                    float u  = upre[r];
                    float hn = u*h2fl[b*8 + col] + (1.f - u)*cc;
                    h2fl[b*8 + col] = hn;
                    stg[b*8 + col] = f2bf(hn);
                    y2g[((size_t)sb + b)*256 + gcol] = hn + y1fl[b*8 + col];
                }
            }
            CBAR();
            if(lane < 32){
                int c = lane, row2 = m*16 + (c>>1), cg = c & 1;
                st8(A_y1h2 + row2*512 + 256 + p*8 + cg*4, pack4(stg + row2*8 + cg*4));
            }
        }
    }
}

// ---------------- K6: output_mel = y2 @ Wo + bo ----------------
__global__ __launch_bounds__(256) void k_omel(const float* __restrict__ y2g,
                                              const float* __restrict__ Wo,
                                              const float* __restrict__ bo,
                                              float* __restrict__ out_mel){
    __shared__ float y8[8][256];
    const int r0 = blockIdx.x * 8;
    const int tid = threadIdx.x;
    for(int i=tid; i<8*256; i+=256){ int r=i>>8, k=i&255; y8[r][k] = y2g[(size_t)(r0+r)*256 + k]; }
    __syncthreads();
    float aA[8], aB[8], aC[8];
    #pragma unroll
    for(int r=0;r<8;++r){ aA[r]=0.f; aB[r]=0.f; aC[r]=0.f; }
    for(int k=0;k<256;++k){
        float wA = Wo[(size_t)k*640 + tid];
        float wB = Wo[(size_t)k*640 + tid + 256];
        float wC = (tid < 128) ? Wo[(size_t)k*640 + tid + 512] : 0.f;
        #pragma unroll
        for(int r=0;r<8;++r){
            float yv = y8[r][k];
            aA[r]=fmaf(yv,wA,aA[r]); aB[r]=fmaf(yv,wB,aB[r]); aC[r]=fmaf(yv,wC,aC[r]);
        }
    }
    float bA = bo[tid], bB = bo[tid+256], bC = (tid<128)? bo[tid+512] : 0.f;
    #pragma unroll
    for(int r=0;r<8;++r){
        int row = r0 + r, s = row >> 5, b = row & 31;
        int mm = tid & 127;
        out_mel[((size_t)b*TOUT_ + s*R_ + (tid>>7))*MEL_ + mm]     = aA[r] + bA;
        out_mel[((size_t)b*TOUT_ + s*R_ + 2 + (tid>>7))*MEL_ + mm] = aB[r] + bB;
        if(tid < 128)
            out_mel[((size_t)b*TOUT_ + s*R_ + 4)*MEL_ + tid]       = aC[r] + bC;
    }
}

// ---------------- K7: output_spec = mel @ Wspec + bspec ----------------
__global__ __launch_bounds__(256) void k_spec(const float* __restrict__ out_mel,
                                              const float* __restrict__ Wspec,
                                              const float* __restrict__ bspec,
                                              float* __restrict__ out_spec){
    __shared__ float m8[8][128];
    const int r0 = blockIdx.x * 8;
    const int tid = threadIdx.x;
    for(int i=tid; i<8*128; i+=256){ int r=i>>7, k=i&127; m8[r][k] = out_mel[(size_t)(r0+r)*128 + k]; }
    __syncthreads();
    float aA[8], aB[8], aC[8];
    #pragma unroll
    for(int r=0;r<8;++r){ aA[r]=0.f; aB[r]=0.f; aC[r]=0.f; }
    for(int k=0;k<128;++k){
        float wA = Wspec[(size_t)k*SPEC_ + tid];
        float wB = Wspec[(size_t)k*SPEC_ + 256 + tid];
        float wC = (tid == 0) ? Wspec[(size_t)k*SPEC_ + 512] : 0.f;
        #pragma unroll
        for(int r=0;r<8;++r){
            float mv = m8[r][k];
            aA[r]=fmaf(mv,wA,aA[r]); aB[r]=fmaf(mv,wB,aB[r]); aC[r]=fmaf(mv,wC,aC[r]);
        }
    }
    float bA = bspec[tid], bB = bspec[256+tid];
    #pragma unroll
    for(int r=0;r<8;++r){
        size_t row = (size_t)(r0 + r);
        out_spec[row*SPEC_ + tid]       = aA[r] + bA;
        out_spec[row*SPEC_ + 256 + tid] = aB[r] + bB;
        if(tid == 0) out_spec[row*SPEC_ + 512] = aC[r] + bspec[512];
    }
}

// ---------------- launcher ----------------
extern "C" void kernel_launch(void* const* d_in, const int* in_sizes, int n_in,
                              void* d_out, int out_size, void* d_ws, size_t ws_size,
                              hipStream_t stream) {
    const float* enc       = (const float*)d_in[0];
    const float* st        = (const float*)d_in[1];
    const float* mg        = (const float*)d_in[2];
    const int*   speaker   = (const int*)  d_in[3];
    const int*   inp_mask  = (const int*)  d_in[4];
    const float* spk_embed = (const float*)d_in[5];
    const float* Wp1=(const float*)d_in[6],  *bp1=(const float*)d_in[7];
    const float* Wp2=(const float*)d_in[8],  *bp2=(const float*)d_in[9];
    const float* Wg_att=(const float*)d_in[10], *bg_att=(const float*)d_in[11];
    const float* Wc_att=(const float*)d_in[12], *bc_att=(const float*)d_in[13];
    const float* Wk=(const float*)d_in[14], *Wq=(const float*)d_in[15], *v_att=(const float*)d_in[16];
    const float* Ws_pre=(const float*)d_in[17], *bs_pre=(const float*)d_in[18];
    const float* Wk_s=(const float*)d_in[19], *Wq_s=(const float*)d_in[20], *v_s=(const float*)d_in[21];
    const float* Wa=(const float*)d_in[22], *ba=(const float*)d_in[23];
    const float* Wg1=(const float*)d_in[24], *bg1=(const float*)d_in[25];
    const float* Wc1=(const float*)d_in[26], *bc1=(const float*)d_in[27];
    const float* Wg2=(const float*)d_in[28], *bg2=(const float*)d_in[29];
    const float* Wc2=(const float*)d_in[30], *bc2=(const float*)d_in[31];
    const float* Wo=(const float*)d_in[32], *bo=(const float*)d_in[33];
    const float* Wspec=(const float*)d_in[34], *bspec=(const float*)d_in[35];

    float* out       = (float*)d_out;
    float* out_mel   = out;             // 32*500*128
    float* out_spec  = out + 2048000;   // 32*500*513
    float* out_alpha = out + 10256000;  // 32*100*128

    char* ws = (char*)d_ws;
    float*    spk_sel = (float*)(ws + OFF_SPK2);
    float*    aco_spk = (float*)(ws + OFF_ACOSPK2);
    float*    ms_g    = (float*)(ws + OFF_MS2);
    float*    ks_g    = (float*)(ws + OFF_KS2);
    float*    preg    = (float*)(ws + OFF_PREG2);
    float*    prec    = (float*)(ws + OFF_PREC2);
    float*    y2g     = (float*)(ws + OFF_Y2G);
    ushort_t* keysb   = (ushort_t*)(ws + OFF_KEYSP);
    ushort_t* encb    = (ushort_t*)(ws + OFF_ENCP);
    ushort_t* wqb     = (ushort_t*)(ws + OFF_WQB);

    hipMemsetAsync(d_ws, 0, ZB_END, stream);

    k_small<<<dim3(1), dim3(256), 0, stream>>>(st, Ws_pre, bs_pre, Wk_s, spk_embed,
                                               speaker, Wa, ba, spk_sel, aco_spk, ms_g, ks_g);
    k_keys   <<<dim3(256),  dim3(256), 0, stream>>>(enc, Wk, keysb);
    k_cvt_enc<<<dim3(4096), dim3(256), 0, stream>>>(enc, encb);
    k_cvt_wq <<<dim3(256),  dim3(256), 0, stream>>>(Wq, wqb);
    k_prenet <<<dim3(200),  dim3(256), 0, stream>>>(mg, spk_sel, Wp1, bp1, Wp2, bp2,
                                                    Wg_att, bg_att, Wc_att, bc_att, preg, prec);
    k_scan_coop<<<dim3(NWG_), dim3(512), 0, stream>>>(ws, Wg_att, Wc_att, Wq_s,
                                                      v_att, v_s, Wa, Wg1, Wc1, Wg2, Wc2,
                                                      bg1, bc1, bg2, bc2, inp_mask, out_alpha);
    k_omel <<<dim3(400),  dim3(256), 0, stream>>>(y2g, Wo, bo, out_mel);
    k_spec <<<dim3(2000), dim3(256), 0, stream>>>(out_mel, Wspec, bspec, out_spec);
}

// Round 8
// 3787.967 us; speedup vs baseline: 1.0918x; 1.0918x over previous
//
#include <hip/hip_runtime.h>

typedef unsigned short ushort_t;
typedef unsigned int   uint_t;
typedef unsigned long long u64;
typedef __attribute__((ext_vector_type(8))) short  bf16x8;
typedef __attribute__((ext_vector_type(4))) float  f32x4;

#define B_      32
#define TIN_    128
#define TOUT_   500
#define R_      5
#define STEPS_  100
#define MEL_    128
#define SPEC_   513
#define NWG_    32

// ---------------- ws layout (bytes) ----------------
// zeroed each launch:
#define ZB_SLOTS   0          // 32*32 int (128B stride per WG)
#define ZB_AH      8192       // [32][256] bf16  h_att
#define ZB_ARH     24576      // [32][256] bf16  r*h_att
#define ZB_AHC     40960      // [32][512] bf16  [h_att | ctx]
#define ZB_AXH1    73728      // [32][512] bf16  [aco | h1]
#define ZB_AXRH1   106496     // [32][512] bf16  [aco | r*h1]
#define ZB_AY1H2   139264     // [32][512] bf16  [y1 | h2]
#define ZB_AY1RH2  172032     // [32][512] bf16  [y1 | r*h2]
#define ZB_UBUF    221184     // [32][256] f32   u gates att
#define ZB_U1BUF   253952     // [32][256] f32
#define ZB_U2BUF   286720     // [32][256] f32
#define ZB_QSBUF   335872     // [32][2] f32 (padded)
#define ZB_END     435200
// written by prep kernels:
#define OFF_ACOSPK2 505856    // 32*256 f32
#define OFF_MS2     538624    // 20 f32
#define OFF_KS2     539136    // 20 f32
#define OFF_SPK2    501760    // 32*32 f32
#define OFF_PREG2   539648    // 100*32*512 f32
#define OFF_PREC2   7093248   // 100*32*256 f32
#define OFF_Y2G     10370048  // 100*32*256 f32
#define OFF_KEYSP   13646848  // [32 b][128 t][256] bf16 (plain)
#define OFF_ENCP    15744000  // [32 b][128 t][256] bf16 (plain)
#define OFF_WQB     17841152  // wq tiled: [k/8][256][8] bf16
// end 17,972,224

// ---------------- helpers ----------------
__device__ __forceinline__ float bf1(ushort_t u){ return __uint_as_float(((uint_t)u) << 16); }
__device__ __forceinline__ ushort_t f2bf(float f){
    uint_t b = __float_as_uint(f);
    uint_t r = (b + 0x7fffu + ((b >> 16) & 1u)) >> 16;
    return (ushort_t)r;
}
__device__ __forceinline__ float fexp2(float x){ return __builtin_amdgcn_exp2f(x); }
__device__ __forceinline__ float frcp(float x){ return __builtin_amdgcn_rcpf(x); }
__device__ __forceinline__ float sigm_f(float x){ return frcp(1.f + fexp2(-1.44269504f * x)); }
__device__ __forceinline__ float tanh_f(float x){
    float e = fexp2(2.88539008f * x);
    return 1.f - 2.f * frcp(e + 1.f);
}
// LLC-coherent relaxed agent atomics for ALL cross-WG data (bypass L1/L2).
__device__ __forceinline__ u64 ld8(const void* p){
    return __hip_atomic_load((const u64*)p, __ATOMIC_RELAXED, __HIP_MEMORY_SCOPE_AGENT);
}
__device__ __forceinline__ void st8(void* p, u64 v){
    __hip_atomic_store((u64*)p, v, __ATOMIC_RELAXED, __HIP_MEMORY_SCOPE_AGENT);
}
__device__ __forceinline__ float ld4f(const void* p){
    uint_t u = __hip_atomic_load((const uint_t*)p, __ATOMIC_RELAXED, __HIP_MEMORY_SCOPE_AGENT);
    return __uint_as_float(u);
}
__device__ __forceinline__ void st4f(void* p, float v){
    __hip_atomic_store((uint_t*)p, __float_as_uint(v), __ATOMIC_RELAXED, __HIP_MEMORY_SCOPE_AGENT);
}
__device__ __forceinline__ float u64lo(u64 v){ return __uint_as_float((uint_t)v); }
__device__ __forceinline__ float u64hi(u64 v){ return __uint_as_float((uint_t)(v >> 32)); }
// Same-type LDS reads packed in registers (no u64 punning of ushort/float LDS).
__device__ __forceinline__ u64 pack4(const ushort_t* q){
    return (u64)q[0] | ((u64)q[1] << 16) | ((u64)q[2] << 32) | ((u64)q[3] << 48);
}
__device__ __forceinline__ u64 pack2f(const float* f){
    return (u64)__float_as_uint(f[0]) | ((u64)__float_as_uint(f[1]) << 32);
}
#define CBAR() asm volatile("" ::: "memory")

// ---------------- K1: tiny constants ----------------
__global__ __launch_bounds__(256) void k_small(
    const float* __restrict__ st, const float* __restrict__ Ws_pre,
    const float* __restrict__ bs_pre, const float* __restrict__ Wk_s,
    const float* __restrict__ spk_embed, const int* __restrict__ speaker,
    const float* __restrict__ Wa, const float* __restrict__ ba,
    float* __restrict__ spk_sel, float* __restrict__ aco_spk,
    float* __restrict__ ms_g, float* __restrict__ ks_g)
{
    __shared__ float spk_l[B_*32];
    __shared__ float ms_l[20];
    const int tid = threadIdx.x;
    for(int i=tid; i<B_*32; i+=256){
        int b = i >> 5, j = i & 31;
        float v = spk_embed[speaker[b]*32 + j];
        spk_l[i] = v; spk_sel[i] = v;
    }
    if(tid < 20){
        int n = tid >> 1, j = tid & 1;
        float v = st[n*2]*Ws_pre[j] + st[n*2+1]*Ws_pre[2+j] + bs_pre[j];
        v = fmaxf(v, 0.f);
        ms_l[tid] = v; ms_g[tid] = v;
    }
    __syncthreads();
    if(tid < 20){
        int n = tid >> 1, j = tid & 1;
        ks_g[tid] = ms_l[n*2]*Wk_s[j] + ms_l[n*2+1]*Wk_s[2+j];
    }
    for(int i=tid; i<B_*256; i+=256){
        int b = i >> 8, n = i & 255;
        float acc = ba[n];
        #pragma unroll
        for(int k=0;k<32;++k) acc = fmaf(spk_l[b*32+k], Wa[(256+k)*256 + n], acc);
        aco_spk[i] = acc;
    }
}

// ---------------- K4: keys = enc @ Wk -> bf16 plain [b][t][256] ----------------
__global__ __launch_bounds__(256) void k_keys(const float* __restrict__ enc,
                                              const float* __restrict__ Wk,
                                              ushort_t* __restrict__ keysb){
    __shared__ float x16[16][256];
    const int bid = blockIdx.x;      // 256 = 32 b * 8 tgroups
    const int b = bid >> 3, tg = bid & 7, t0 = tg*16;
    const int tid = threadIdx.x;
    for(int i=tid; i<16*256; i+=256){
        int r = i >> 8, k = i & 255;
        x16[r][k] = enc[((size_t)b*TIN_ + t0 + r)*256 + k];
    }
    __syncthreads();
    float acc[16];
    #pragma unroll
    for(int r=0;r<16;++r) acc[r] = 0.f;
    for(int k=0;k<256;++k){
        float w = Wk[k*256 + tid];
        #pragma unroll
        for(int r=0;r<16;++r) acc[r] = fmaf(x16[r][k], w, acc[r]);
    }
    #pragma unroll
    for(int r=0;r<16;++r)
        keysb[((size_t)b*TIN_ + t0 + r)*256 + tid] = f2bf(acc[r]);
}

// ---------------- converters ----------------
__global__ __launch_bounds__(256) void k_cvt_enc(const float* __restrict__ enc,
                                                 ushort_t* __restrict__ encb){
    int o = blockIdx.x*256 + threadIdx.x;      // 4096 blocks
    encb[o] = f2bf(enc[o]);
}
// wq tiled: dst[(k>>3)*2048 + c*8 + (k&7)] — bf16x8-coalesced column streams
__global__ __launch_bounds__(256) void k_cvt_wq(const float* __restrict__ Wq,
                                                ushort_t* __restrict__ wqT){
    int o = blockIdx.x*256 + threadIdx.x;      // 256 blocks -> 65536
    int k = o >> 8, c = o & 255;
    wqT[(k>>3)*2048 + c*8 + (k&7)] = f2bf(Wq[k*256 + c]);
}

// ---------------- K3: prenet + x-part of att-GRU for all steps ----------------
__global__ __launch_bounds__(256) void k_prenet(
    const float* __restrict__ mg, const float* __restrict__ spk_sel,
    const float* __restrict__ Wp1, const float* __restrict__ bp1,
    const float* __restrict__ Wp2, const float* __restrict__ bp2,
    const float* __restrict__ Wg_att, const float* __restrict__ bg_att,
    const float* __restrict__ Wc_att, const float* __restrict__ bc_att,
    float* __restrict__ preg, float* __restrict__ prec)
{
    __shared__ float fr[16][128];
    __shared__ float p1[16][256];
    __shared__ float p2[16][128];
    __shared__ float spk_l[16][32];
    const int r0 = blockIdx.x * 16;
    const int tid = threadIdx.x;
    for(int i=tid; i<16*128; i+=256){
        int r = i >> 7, mcol = i & 127;
        int row = r0 + r, s = row >> 5, b = row & 31;
        fr[r][mcol] = (s == 0) ? 0.f : mg[((size_t)b*TOUT_ + s*R_ - 1)*MEL_ + mcol];
    }
    for(int i=tid; i<16*32; i+=256){
        int r = i >> 5, j = i & 31;
        spk_l[r][j] = spk_sel[((r0 + r) & 31)*32 + j];
    }
    __syncthreads();
    {
        float acc[16];
        #pragma unroll
        for(int r=0;r<16;++r) acc[r]=0.f;
        for(int k=0;k<128;++k){
            float w = Wp1[k*256 + tid];
            #pragma unroll
            for(int r=0;r<16;++r) acc[r] = fmaf(fr[r][k], w, acc[r]);
        }
        float bb = bp1[tid];
        #pragma unroll
        for(int r=0;r<16;++r) p1[r][tid] = fmaxf(acc[r] + bb, 0.f);
    }
    __syncthreads();
    if(tid < 128){
        float acc[16];
        #pragma unroll
        for(int r=0;r<16;++r) acc[r]=0.f;
        for(int k=0;k<256;++k){
            float w = Wp2[k*128 + tid];
            #pragma unroll
            for(int r=0;r<16;++r) acc[r] = fmaf(p1[r][k], w, acc[r]);
        }
        float bb = bp2[tid];
        #pragma unroll
        for(int r=0;r<16;++r) p2[r][tid] = fmaxf(acc[r] + bb, 0.f);
    }
    __syncthreads();
    {
        float aA[16], aB[16];
        #pragma unroll
        for(int r=0;r<16;++r){ aA[r]=0.f; aB[r]=0.f; }
        for(int k=0;k<128;++k){
            float wA = Wg_att[k*512 + tid], wB = Wg_att[k*512 + tid + 256];
            #pragma unroll
            for(int r=0;r<16;++r){ float pv = p2[r][k]; aA[r]=fmaf(pv,wA,aA[r]); aB[r]=fmaf(pv,wB,aB[r]); }
        }
        for(int k=0;k<32;++k){
            float wA = Wg_att[(128+k)*512 + tid], wB = Wg_att[(128+k)*512 + tid + 256];
            #pragma unroll
            for(int r=0;r<16;++r){ float sv = spk_l[r][k]; aA[r]=fmaf(sv,wA,aA[r]); aB[r]=fmaf(sv,wB,aB[r]); }
        }
        float bA = bg_att[tid], bB = bg_att[tid + 256];
        #pragma unroll
        for(int r=0;r<16;++r){
            preg[(size_t)(r0+r)*512 + tid]       = aA[r] + bA;
            preg[(size_t)(r0+r)*512 + tid + 256] = aB[r] + bB;
        }
    }
    {
        float acc[16];
        #pragma unroll
        for(int r=0;r<16;++r) acc[r]=0.f;
        for(int k=0;k<128;++k){
            float w = Wc_att[k*256 + tid];
            #pragma unroll
            for(int r=0;r<16;++r) acc[r] = fmaf(p2[r][k], w, acc[r]);
        }
        for(int k=0;k<32;++k){
            float w = Wc_att[(128+k)*256 + tid];
            #pragma unroll
            for(int r=0;r<16;++r) acc[r] = fmaf(spk_l[r][k], w, acc[r]);
        }
        float bb = bc_att[tid];
        #pragma unroll
        for(int r=0;r<16;++r) prec[(size_t)(r0+r)*256 + tid] = acc[r] + bb;
    }
}

// ---------------- cooperative scan helpers ----------------
// Barrier: per-wave vmcnt drain + RELEASE flag store (writer-side drain to the
// coherence point, proven in r7) + RELAXED polls. NO acquire fence: all
// cross-WG data reads are sc1 (LLC-direct), so reader caches can never be
// stale — and L2 stays warm for read-only streams (keys/enc/wq/preg/prec).
__device__ __forceinline__ void gridbar(int* slots, int p, int seq, int tid){
    asm volatile("s_waitcnt vmcnt(0)" ::: "memory");
    __syncthreads();
    if(tid == 0)
        __hip_atomic_store(&slots[p*32], seq, __ATOMIC_RELEASE, __HIP_MEMORY_SCOPE_AGENT);
    if(tid < NWG_){
        while(__hip_atomic_load(&slots[tid*32], __ATOMIC_RELAXED, __HIP_MEMORY_SCOPE_AGENT) < seq)
            __builtin_amdgcn_s_sleep(1);
    }
    __syncthreads();
}

__device__ __forceinline__ void loadW(const float* W, int ldw, int rowbase, int nk, int kbase,
                                      int Ktot, int col0, int ncols, ushort_t* lds, int tid){
    for(int e = tid; e < 16*nk; e += 512){
        int col = e & 15, k = e >> 4;
        ushort_t v = 0;
        if(col < ncols) v = f2bf(W[(size_t)(rowbase + k)*ldw + col0 + col]);
        lds[(col*Ktot + kbase + k) ^ ((col & 7) << 3)] = v;
    }
}

template<int K>
__device__ __forceinline__ f32x4 do_gemm(const ushort_t* Ab, const ushort_t* Wl, float* red,
                                         int m, int kq, int lane){
    const int row = m*16 + (lane & 15);
    const int col = lane & 15;
    const int ko  = (lane >> 4) * 8;
    u64 av[K/64];
    #pragma unroll
    for(int t = 0; t < K/128; ++t){
        const int k0 = kq*(K/4) + t*32 + ko;
        av[2*t]   = ld8(Ab + row*K + k0);
        av[2*t+1] = ld8(Ab + row*K + k0 + 4);
    }
    f32x4 acc = {0.f,0.f,0.f,0.f};
    #pragma unroll
    for(int t = 0; t < K/128; ++t){
        const int k0 = kq*(K/4) + t*32 + ko;
        union { u64 q[2]; bf16x8 v; } ua;
        ua.q[0] = av[2*t]; ua.q[1] = av[2*t+1];
        bf16x8 b = *reinterpret_cast<const bf16x8*>(Wl + ((col*K + k0) ^ ((col & 7) << 3)));
        acc = __builtin_amdgcn_mfma_f32_16x16x32_bf16(ua.v, b, acc, 0, 0, 0);
    }
    if(kq > 0) *reinterpret_cast<f32x4*>(red + ((kq-1)*2 + m)*256 + lane*4) = acc;
    __syncthreads();
    if(kq == 0){
        #pragma unroll
        for(int j = 0; j < 3; ++j)
            acc += *reinterpret_cast<const f32x4*>(red + (j*2 + m)*256 + lane*4);
    }
    return acc;
}

// ---------------- K5: the cooperative scan ----------------
__global__ __launch_bounds__(512) void k_scan_coop(
    char* ws,
    const float* __restrict__ Wg_att, const float* __restrict__ Wc_att,
    const float* __restrict__ Wq_s,
    const float* __restrict__ v_att, const float* __restrict__ v_s,
    const float* __restrict__ Wa,
    const float* __restrict__ Wg1, const float* __restrict__ Wc1,
    const float* __restrict__ Wg2, const float* __restrict__ Wc2,
    const float* __restrict__ bg1, const float* __restrict__ bc1,
    const float* __restrict__ bg2, const float* __restrict__ bc2,
    const int* __restrict__ inp_mask, float* __restrict__ out_alpha)
{
    const int p = blockIdx.x, tid = threadIdx.x;
    const int lane = tid & 63, wv = tid >> 6;
    const int m = wv & 1, kq = wv >> 1;

    int* slots       = (int*)(ws + ZB_SLOTS);
    ushort_t* A_h    = (ushort_t*)(ws + ZB_AH);
    ushort_t* A_rh   = (ushort_t*)(ws + ZB_ARH);
    ushort_t* A_hc   = (ushort_t*)(ws + ZB_AHC);
    ushort_t* A_xh1  = (ushort_t*)(ws + ZB_AXH1);
    ushort_t* A_xrh1 = (ushort_t*)(ws + ZB_AXRH1);
    ushort_t* A_y1h2 = (ushort_t*)(ws + ZB_AY1H2);
    ushort_t* A_y1rh2= (ushort_t*)(ws + ZB_AY1RH2);
    float* ubuf  = (float*)(ws + ZB_UBUF);
    float* u1buf = (float*)(ws + ZB_U1BUF);
    float* u2buf = (float*)(ws + ZB_U2BUF);
    float* qsbuf = (float*)(ws + ZB_QSBUF);
    const float* acospk = (const float*)(ws + OFF_ACOSPK2);
    const float* msg    = (const float*)(ws + OFF_MS2);
    const float* ksg    = (const float*)(ws + OFF_KS2);
    const float* preg   = (const float*)(ws + OFF_PREG2);
    const float* prec   = (const float*)(ws + OFF_PREC2);
    float* y2g          = (float*)(ws + OFF_Y2G);
    const ushort_t* keysb = (const ushort_t*)(ws + OFF_KEYSP);
    const ushort_t* encb  = (const ushort_t*)(ws + OFF_ENCP);
    const ushort_t* wqT   = (const ushort_t*)(ws + OFF_WQB);

    // LDS: resident weight slices (col-major [16][K], bf16, swizzled)
    __shared__ ushort_t wA[16*256], wB[16*256];
    __shared__ ushort_t wG[16*512], wH[16*512], wI[16*512], wJ[16*512], wK[16*512];
    __shared__ __align__(16) char uni[16384];  // red/CDE scratch | stg(@8K) | stgf(@10K)
    float* red = (float*)uni;
    float* uf  = (float*)uni;
    ushort_t* stg  = (ushort_t*)(uni + 8192);   // bf16 pack tile
    float*    stgf = (float*)(uni + 10240);     // f32 pack tile
    __shared__ float vatt_l[256];
    __shared__ float msks[48];
    __shared__ float ctxs_l[64];
    __shared__ float acosl[256], acofl[256], y1fl[256];
    __shared__ float hfl[256], h1fl[256], h2fl[256];
    __shared__ float bg1s[16], bc1s[8], bg2s[16], bc2s[8], wasl[16];
    __shared__ float wqs_l[512];

    loadW(Wg_att, 512, 160, 256, 0, 256, p*16, 16, wA, tid);
    loadW(Wc_att, 256, 160, 256, 0, 256, p*8,  8,  wB, tid);
    loadW(Wa,     256, 0,   256, 0,   512, p*8, 8, wG, tid);   // rows 0..255  (h)
    loadW(Wa,     256, 288, 256, 256, 512, p*8, 8, wG, tid);   // rows 288..543 (ctx)
    loadW(Wg1,    512, 0,   512, 0, 512, p*16, 16, wH, tid);
    loadW(Wc1,    256, 0,   512, 0, 512, p*8,  8,  wI, tid);
    loadW(Wg2,    512, 0,   512, 0, 512, p*16, 16, wJ, tid);
    loadW(Wc2,    256, 0,   512, 0, 512, p*8,  8,  wK, tid);
    if(tid < 256){
        vatt_l[tid] = v_att[tid];
        acosl[tid]  = acospk[(tid>>3)*256 + p*8 + (tid&7)];
        hfl[tid] = 0.f; h1fl[tid] = 0.f; h2fl[tid] = 0.f;
    }
    wqs_l[tid] = Wq_s[tid];
    if(tid < 20) msks[tid] = msg[tid];
    if(tid >= 20 && tid < 40) msks[tid] = ksg[tid-20];
    if(tid == 40) msks[40] = v_s[0];
    if(tid == 41) msks[41] = v_s[1];
    if(tid < 16){ bg1s[tid] = bg1[p*16+tid]; bg2s[tid] = bg2[p*16+tid]; }
    if(tid < 8){ bc1s[tid] = bc1[p*8+tid]; bc2s[tid] = bc2[p*8+tid]; }
    if(tid < 16) wasl[tid] = Wa[(size_t)(544 + (tid & 1))*256 + p*8 + (tid >> 1)];
    const int maskp = inp_mask[p];
    __syncthreads();

    int seq = 0;
    for(int s = 0; s < STEPS_; ++s){
        const int sb = s*32;
        const int col = lane & 15;
        const int bbase = m*16 + ((lane>>4)<<2);
        // ---- A: att-GRU gates ----
        __syncthreads();   // red WAR guard vs stage K
        u64 hpre[4];
        if(kq == 0 && p < 16){
            #pragma unroll
            for(int r=0;r<4;++r) hpre[r] = ld8(A_h + (bbase+r)*256 + ((p*16+col) & ~3));
        }
        f32x4 acc = do_gemm<256>(A_h, wA, red, m, kq, lane);
        if(kq == 0){
            const int gcol = p*16 + col;
            if(p < 16){
                #pragma unroll
                for(int r=0;r<4;++r){
                    int b = bbase + r;
                    float g = sigm_f(acc[r] + preg[(size_t)(sb + b)*512 + gcol]);
                    float hb = bf1((ushort_t)(hpre[r] >> ((col & 3)*16)));
                    stg[b*16 + col] = f2bf(g * hb);
                }
                CBAR();
                int c = lane, row2 = m*16 + (c>>2), cg = c & 3;
                st8(A_rh + row2*256 + p*16 + cg*4, pack4(stg + row2*16 + cg*4));
            } else {
                #pragma unroll
                for(int r=0;r<4;++r){
                    int b = bbase + r;
                    stgf[b*16 + col] = sigm_f(acc[r] + preg[(size_t)(sb + b)*512 + gcol]);
                }
                CBAR();
                #pragma unroll
                for(int j=0;j<2;++j){
                    int c = lane*2 + j, row2 = m*16 + (c>>3), cg = c & 7;
                    st8(ubuf + row2*256 + (p-16)*16 + cg*2, pack2f(stgf + row2*16 + cg*2));
                }
            }
        }
        gridbar(slots, p, ++seq, tid);   // b1
        // ---- B: att-GRU candidate + h update ----
        float upre[4];
        if(kq == 0 && col < 8){
            #pragma unroll
            for(int r=0;r<4;++r) upre[r] = ld4f(ubuf + (bbase+r)*256 + p*8 + col);
        }
        acc = do_gemm<256>(A_rh, wB, red, m, kq, lane);
        if(kq == 0){
            if(col < 8){
                const int gcol = p*8 + col;
                #pragma unroll
                for(int r=0;r<4;++r){
                    int b = bbase + r;
                    float cc = tanh_f(acc[r] + prec[(size_t)(sb + b)*256 + gcol]);
                    float u  = upre[r];
                    float hn = u*hfl[b*8 + col] + (1.f - u)*cc;
                    hfl[b*8 + col] = hn;
                    stg[b*8 + col] = f2bf(hn);
                }
            }
            CBAR();
            if(lane < 32){
                int c = lane, row2 = m*16 + (c>>1), cg = c & 1;
                u64 v = pack4(stg + row2*8 + cg*4);
                st8(A_h  + row2*256 + p*8 + cg*4, v);
                st8(A_hc + row2*512 + p*8 + cg*4, v);
            }
        }
        gridbar(slots, p, ++seq, tid);   // b2
        // ---- CDE: row-split attention for row p (no cross-WG exchange) ----
        {
            float* hrow   = uf;            // [256]
            float* qpart  = uf + 256;      // [512]
            float* qrow   = uf + 768;      // [256]
            float* escore = uf + 1024;     // [128]
            float* alphaA = uf + 1152;     // [128]
            float* smv    = uf + 1280;     // [1]
            float* cpart  = uf + 1536;     // [512]
            if(tid < 64){
                u64 h4 = ld8(A_h + p*256 + tid*4);
                #pragma unroll
                for(int j=0;j<4;++j) hrow[tid*4+j] = bf1((ushort_t)(h4 >> (j*16)));
            }
            __syncthreads();
            {   // qW partial GEMV: tiled wqT, bf16x8 coalesced (L2-warm)
                int colq = tid & 255, kh = tid >> 8;
                const ushort_t* wq = wqT + kh*32768 + colq*8;
                float accq = 0.f;
                #pragma unroll 4
                for(int k8=0;k8<16;++k8){
                    bf16x8 w = *(const bf16x8*)(wq + k8*2048);
                    #pragma unroll
                    for(int j=0;j<8;++j)
                        accq = fmaf(hrow[kh*128 + k8*8 + j], bf1((ushort_t)w[j]), accq);
                }
                qpart[kh*256 + colq] = accq;
            }
            // style query + style context (lanes 0..15 of wave 0)
            if(tid < 16){
                float q0s=0.f, q1s=0.f;
                #pragma unroll
                for(int kk=0;kk<16;++kk){
                    int k = tid*16 + kk; float hv = hrow[k];
                    q0s = fmaf(hv, wqs_l[k*2],   q0s);
                    q1s = fmaf(hv, wqs_l[k*2+1], q1s);
                }
                #pragma unroll
                for(int d=1; d<16; d<<=1){ q0s += __shfl_xor(q0s,d,64); q1s += __shfl_xor(q1s,d,64); }
                if(tid == 0){
                    float es[10]; float mx = -1e30f;
                    #pragma unroll
                    for(int n=0;n<10;++n){
                        float t = msks[40]*tanh_f(msks[20+n*2] + q0s) + msks[41]*tanh_f(msks[20+n*2+1] + q1s);
                        es[n] = t; mx = fmaxf(mx, t);
                    }
                    float sum = 0.f;
                    #pragma unroll
                    for(int n=0;n<10;++n){ float pe = fexp2((es[n]-mx)*1.44269504f); es[n]=pe; sum += pe; }
                    float inv = frcp(sum); float c0=0.f, c1=0.f;
                    #pragma unroll
                    for(int n=0;n<10;++n){ float al = es[n]*inv; c0 = fmaf(al, msks[n*2], c0); c1 = fmaf(al, msks[n*2+1], c1); }
                    float pr2[2] = {c0, c1};
                    st8(qsbuf + p*2, pack2f(pr2));
                }
            }
            __syncthreads();
            if(tid < 256) qrow[tid] = qpart[tid] + qpart[256+tid];
            __syncthreads();
            {   // scores: t = tid>>2 (128), q = tid&3 (64-a chunk)
                int t = tid >> 2, q = tid & 3;
                const ushort_t* kp = keysb + ((size_t)(p*TIN_ + t))*256 + q*64;
                float e = 0.f;
                #pragma unroll
                for(int i2=0;i2<8;++i2){
                    bf16x8 kv = *(const bf16x8*)(kp + i2*8);
                    #pragma unroll
                    for(int j=0;j<8;++j){
                        int a = q*64 + i2*8 + j;
                        e = fmaf(vatt_l[a], tanh_f(bf1((ushort_t)kv[j]) + qrow[a]), e);
                    }
                }
                e += __shfl_xor(e,1,64); e += __shfl_xor(e,2,64);
                if(q == 0) escore[t] = (t < maskp) ? e : -1e9f;
            }
            __syncthreads();
            if(tid < 64){
                float e0 = escore[tid], e1 = escore[tid+64];
                float mx = fmaxf(e0, e1);
                #pragma unroll
                for(int d=1; d<64; d<<=1) mx = fmaxf(mx, __shfl_xor(mx,d,64));
                float a0 = fexp2((e0-mx)*1.44269504f);
                float a1 = fexp2((e1-mx)*1.44269504f);
                alphaA[tid] = a0; alphaA[tid+64] = a1;
                float ssum = a0 + a1;
                #pragma unroll
                for(int d=1; d<64; d<<=1) ssum += __shfl_xor(ssum,d,64);
                if(tid == 0) smv[0] = frcp(ssum);
            }
            __syncthreads();
            if(tid < 128){
                float a = alphaA[tid] * smv[0];
                alphaA[tid] = a;
                st4f(out_alpha + ((size_t)p*STEPS_ + s)*TIN_ + tid, a);
            }
            __syncthreads();
            {   // context partial: col = tid&255, th = tid>>8 sums 64 t
                int colq = tid & 255, th = tid >> 8;
                const ushort_t* ep = encb + ((size_t)(p*TIN_ + th*64))*256 + colq;
                float c = 0.f;
                #pragma unroll 4
                for(int tt=0; tt<64; ++tt) c = fmaf(alphaA[th*64+tt], bf1(ep[(size_t)tt*256]), c);
                cpart[th*256 + colq] = c;
            }
            __syncthreads();
            if(tid < 256) stg[tid] = f2bf(cpart[tid] + cpart[256+tid]);
            CBAR();
            __syncthreads();
            if(tid < 64) st8(A_hc + p*512 + 256 + tid*4, pack4(stg + tid*4));
        }
        gridbar(slots, p, ++seq, tid);   // b3
        // ---- G: aco = [h|ctx]@Wa + acospk + ctx_s@Wa_s ----
        if(tid < 32){
            u64 qq = ld8(qsbuf + tid*2);
            ctxs_l[tid*2] = u64lo(qq); ctxs_l[tid*2+1] = u64hi(qq);
        }
        acc = do_gemm<512>(A_hc, wG, red, m, kq, lane);
        if(kq == 0){
            if(col < 8){
                #pragma unroll
                for(int r=0;r<4;++r){
                    int b = bbase + r;
                    float v = acc[r] + acosl[b*8 + col]
                            + ctxs_l[b*2]   * wasl[col*2]
                            + ctxs_l[b*2+1] * wasl[col*2+1];
                    acofl[b*8 + col] = v;
                    stg[b*8 + col] = f2bf(v);
                }
            }
            CBAR();
            if(lane < 32){
                int c = lane, row2 = m*16 + (c>>1), cg = c & 1;
                u64 v = pack4(stg + row2*8 + cg*4);
                st8(A_xh1  + row2*512 + p*8 + cg*4, v);
                st8(A_xrh1 + row2*512 + p*8 + cg*4, v);
            }
        }
        gridbar(slots, p, ++seq, tid);   // b4
        // ---- H: GRU1 gates ----
        if(kq == 0 && p < 16){
            #pragma unroll
            for(int r=0;r<4;++r) hpre[r] = ld8(A_xh1 + (bbase+r)*512 + 256 + ((p*16+col) & ~3));
        }
        acc = do_gemm<512>(A_xh1, wH, red, m, kq, lane);
        if(kq == 0){
            if(p < 16){
                #pragma unroll
                for(int r=0;r<4;++r){
                    int b = bbase + r;
                    float g = sigm_f(acc[r] + bg1s[col]);
                    float hb = bf1((ushort_t)(hpre[r] >> ((col & 3)*16)));
                    stg[b*16 + col] = f2bf(g * hb);
                }
                CBAR();
                int c = lane, row2 = m*16 + (c>>2), cg = c & 3;
                st8(A_xrh1 + row2*512 + 256 + p*16 + cg*4, pack4(stg + row2*16 + cg*4));
            } else {
                #pragma unroll
                for(int r=0;r<4;++r)
                    stgf[(bbase+r)*16 + col] = sigm_f(acc[r] + bg1s[col]);
                CBAR();
                #pragma unroll
                for(int j=0;j<2;++j){
                    int c = lane*2 + j, row2 = m*16 + (c>>3), cg = c & 7;
                    st8(u1buf + row2*256 + (p-16)*16 + cg*2, pack2f(stgf + row2*16 + cg*2));
                }
            }
        }
        gridbar(slots, p, ++seq, tid);   // b5
        // ---- I: GRU1 candidate + y1 ----
        if(kq == 0 && col < 8){
            #pragma unroll
            for(int r=0;r<4;++r) upre[r] = ld4f(u1buf + (bbase+r)*256 + p*8 + col);
        }
        acc = do_gemm<512>(A_xrh1, wI, red, m, kq, lane);
        if(kq == 0){
            if(col < 8){
                #pragma unroll
                for(int r=0;r<4;++r){
                    int b = bbase + r;
                    float cc = tanh_f(acc[r] + bc1s[col]);
                    float u  = upre[r];
                    float hn = u*h1fl[b*8 + col] + (1.f - u)*cc;
                    h1fl[b*8 + col] = hn;
                    stg[b*8 + col] = f2bf(hn);
                    float y1 = hn + acofl[b*8 + col];
                    y1fl[b*8 + col] = y1;
                    stg[256 + b*8 + col] = f2bf(y1);
                }
            }
            CBAR();
            if(lane < 32){
                int c = lane, row2 = m*16 + (c>>1), cg = c & 1;
                u64 vh = pack4(stg + row2*8 + cg*4);
                u64 vy = pack4(stg + 256 + row2*8 + cg*4);
                st8(A_xh1   + row2*512 + 256 + p*8 + cg*4, vh);
                st8(A_y1h2  + row2*512 + p*8 + cg*4, vy);
                st8(A_y1rh2 + row2*512 + p*8 + cg*4, vy);
            }
        }
        gridbar(slots, p, ++seq, tid);   // b6
        // ---- J: GRU2 gates ----
        if(kq == 0 && p < 16){
            #pragma unroll
            for(int r=0;r<4;++r) hpre[r] = ld8(A_y1h2 + (bbase+r)*512 + 256 + ((p*16+col) & ~3));
        }
        acc = do_gemm<512>(A_y1h2, wJ, red, m, kq, lane);
        if(kq == 0){
            if(p < 16){
                #pragma unroll
                for(int r=0;r<4;++r){
                    int b = bbase + r;
                    float g = sigm_f(acc[r] + bg2s[col]);
                    float hb = bf1((ushort_t)(hpre[r] >> ((col & 3)*16)));
                    stg[b*16 + col] = f2bf(g * hb);
                }
                CBAR();
                int c = lane, row2 = m*16 + (c>>2), cg = c & 3;
                st8(A_y1rh2 + row2*512 + 256 + p*16 + cg*4, pack4(stg + row2*16 + cg*4));
            } else {
                #pragma unroll
                for(int r=0;r<4;++r)
                    stgf[(bbase+r)*16 + col] = sigm_f(acc[r] + bg2s[col]);
                CBAR();
                #pragma unroll
                for(int j=0;j<2;++j){
                    int c = lane*2 + j, row2 = m*16 + (c>>3), cg = c & 7;
                    st8(u2buf + row2*256 + (p-16)*16 + cg*2, pack2f(stgf + row2*16 + cg*2));
                }
            }
        }
        gridbar(slots, p, ++seq, tid);   // b7
        // ---- K: GRU2 candidate + y2 (no barrier; loop-top syncthreads guards red) ----
        if(kq == 0 && col < 8){
            #pragma unroll
            for(int r=0;r<4;++r) upre[r] = ld4f(u2buf + (bbase+r)*256 + p*8 + col);
        }
        acc = do_gemm<512>(A_y1rh2, wK, red, m, kq, lane);
        if(kq == 0){
            if(col < 8){
                const int gcol = p*8 + col;
                #pragma unroll
                for(int r=0;r<4;++r){
                    int b = bbase + r;
                    float cc = tanh_f(acc[r] + bc2s[col]);
                    float u  = upre[r];
                    float hn = u*h2fl[b*8 + col] + (1.f - u)*cc;
                    h2fl[b*8 + col] = hn;
                    stg[b*8 + col] = f2bf(hn);
                    st4f(y2g + ((size_t)sb + b)*256 + gcol, hn + y1fl[b*8 + col]);
                }
            }
            CBAR();
            if(lane < 32){
                int c = lane, row2 = m*16 + (c>>1), cg = c & 1;
                st8(A_y1h2 + row2*512 + 256 + p*8 + cg*4, pack4(stg + row2*8 + cg*4));
            }
        }
    }
}

// ---------------- K6: output_mel = y2 @ Wo + bo ----------------
__global__ __launch_bounds__(256) void k_omel(const float* __restrict__ y2g,
                                              const float* __restrict__ Wo,
                                              const float* __restrict__ bo,
                                              float* __restrict__ out_mel){
    __shared__ float y8[8][256];
    const int r0 = blockIdx.x * 8;
    const int tid = threadIdx.x;
    for(int i=tid; i<8*256; i+=256){ int r=i>>8, k=i&255; y8[r][k] = y2g[(size_t)(r0+r)*256 + k]; }
    __syncthreads();
    float aA[8], aB[8], aC[8];
    #pragma unroll
    for(int r=0;r<8;++r){ aA[r]=0.f; aB[r]=0.f; aC[r]=0.f; }
    for(int k=0;k<256;++k){
        float wA = Wo[(size_t)k*640 + tid];
        float wB = Wo[(size_t)k*640 + tid + 256];
        float wC = (tid < 128) ? Wo[(size_t)k*640 + tid + 512] : 0.f;
        #pragma unroll
        for(int r=0;r<8;++r){
            float yv = y8[r][k];
            aA[r]=fmaf(yv,wA,aA[r]); aB[r]=fmaf(yv,wB,aB[r]); aC[r]=fmaf(yv,wC,aC[r]);
        }
    }
    float bA = bo[tid], bB = bo[tid+256], bC = (tid<128)? bo[tid+512] : 0.f;
    #pragma unroll
    for(int r=0;r<8;++r){
        int row = r0 + r, s = row >> 5, b = row & 31;
        int mm = tid & 127;
        out_mel[((size_t)b*TOUT_ + s*R_ + (tid>>7))*MEL_ + mm]     = aA[r] + bA;
        out_mel[((size_t)b*TOUT_ + s*R_ + 2 + (tid>>7))*MEL_ + mm] = aB[r] + bB;
        if(tid < 128)
            out_mel[((size_t)b*TOUT_ + s*R_ + 4)*MEL_ + tid]       = aC[r] + bC;
    }
}

// ---------------- K7: output_spec = mel @ Wspec + bspec ----------------
__global__ __launch_bounds__(256) void k_spec(const float* __restrict__ out_mel,
                                              const float* __restrict__ Wspec,
                                              const float* __restrict__ bspec,
                                              float* __restrict__ out_spec){
    __shared__ float m8[8][128];
    const int r0 = blockIdx.x * 8;
    const int tid = threadIdx.x;
    for(int i=tid; i<8*128; i+=256){ int r=i>>7, k=i&127; m8[r][k] = out_mel[(size_t)(r0+r)*128 + k]; }
    __syncthreads();
    float aA[8], aB[8], aC[8];
    #pragma unroll
    for(int r=0;r<8;++r){ aA[r]=0.f; aB[r]=0.f; aC[r]=0.f; }
    for(int k=0;k<128;++k){
        float wA = Wspec[(size_t)k*SPEC_ + tid];
        float wB = Wspec[(size_t)k*SPEC_ + 256 + tid];
        float wC = (tid == 0) ? Wspec[(size_t)k*SPEC_ + 512] : 0.f;
        #pragma unroll
        for(int r=0;r<8;++r){
            float mv = m8[r][k];
            aA[r]=fmaf(mv,wA,aA[r]); aB[r]=fmaf(mv,wB,aB[r]); aC[r]=fmaf(mv,wC,aC[r]);
        }
    }
    float bA = bspec[tid], bB = bspec[256+tid];
    #pragma unroll
    for(int r=0;r<8;++r){
        size_t row = (size_t)(r0 + r);
        out_spec[row*SPEC_ + tid]       = aA[r] + bA;
        out_spec[row*SPEC_ + 256 + tid] = aB[r] + bB;
        if(tid == 0) out_spec[row*SPEC_ + 512] = aC[r] + bspec[512];
    }
}

// ---------------- launcher ----------------
extern "C" void kernel_launch(void* const* d_in, const int* in_sizes, int n_in,
                              void* d_out, int out_size, void* d_ws, size_t ws_size,
                              hipStream_t stream) {
    const float* enc       = (const float*)d_in[0];
    const float* st        = (const float*)d_in[1];
    const float* mg        = (const float*)d_in[2];
    const int*   speaker   = (const int*)  d_in[3];
    const int*   inp_mask  = (const int*)  d_in[4];
    const float* spk_embed = (const float*)d_in[5];
    const float* Wp1=(const float*)d_in[6],  *bp1=(const float*)d_in[7];
    const float* Wp2=(const float*)d_in[8],  *bp2=(const float*)d_in[9];
    const float* Wg_att=(const float*)d_in[10], *bg_att=(const float*)d_in[11];
    const float* Wc_att=(const float*)d_in[12], *bc_att=(const float*)d_in[13];
    const float* Wk=(const float*)d_in[14], *Wq=(const float*)d_in[15], *v_att=(const float*)d_in[16];
    const float* Ws_pre=(const float*)d_in[17], *bs_pre=(const float*)d_in[18];
    const float* Wk_s=(const float*)d_in[19], *Wq_s=(const float*)d_in[20], *v_s=(const float*)d_in[21];
    const float* Wa=(const float*)d_in[22], *ba=(const float*)d_in[23];
    const float* Wg1=(const float*)d_in[24], *bg1=(const float*)d_in[25];
    const float* Wc1=(const float*)d_in[26], *bc1=(const float*)d_in[27];
    const float* Wg2=(const float*)d_in[28], *bg2=(const float*)d_in[29];
    const float* Wc2=(const float*)d_in[30], *bc2=(const float*)d_in[31];
    const float* Wo=(const float*)d_in[32], *bo=(const float*)d_in[33];
    const float* Wspec=(const float*)d_in[34], *bspec=(const float*)d_in[35];

    float* out       = (float*)d_out;
    float* out_mel   = out;             // 32*500*128
    float* out_spec  = out + 2048000;   // 32*500*513
    float* out_alpha = out + 10256000;  // 32*100*128

    char* ws = (char*)d_ws;
    float*    spk_sel = (float*)(ws + OFF_SPK2);
    float*    aco_spk = (float*)(ws + OFF_ACOSPK2);
    float*    ms_g    = (float*)(ws + OFF_MS2);
    float*    ks_g    = (float*)(ws + OFF_KS2);
    float*    preg    = (float*)(ws + OFF_PREG2);
    float*    prec    = (float*)(ws + OFF_PREC2);
    float*    y2g     = (float*)(ws + OFF_Y2G);
    ushort_t* keysb   = (ushort_t*)(ws + OFF_KEYSP);
    ushort_t* encb    = (ushort_t*)(ws + OFF_ENCP);
    ushort_t* wqT     = (ushort_t*)(ws + OFF_WQB);

    hipMemsetAsync(d_ws, 0, ZB_END, stream);

    k_small<<<dim3(1), dim3(256), 0, stream>>>(st, Ws_pre, bs_pre, Wk_s, spk_embed,
                                               speaker, Wa, ba, spk_sel, aco_spk, ms_g, ks_g);
    k_keys   <<<dim3(256),  dim3(256), 0, stream>>>(enc, Wk, keysb);
    k_cvt_enc<<<dim3(4096), dim3(256), 0, stream>>>(enc, encb);
    k_cvt_wq <<<dim3(256),  dim3(256), 0, stream>>>(Wq, wqT);
    k_prenet <<<dim3(200),  dim3(256), 0, stream>>>(mg, spk_sel, Wp1, bp1, Wp2, bp2,
                                                    Wg_att, bg_att, Wc_att, bc_att, preg, prec);
    k_scan_coop<<<dim3(NWG_), dim3(512), 0, stream>>>(ws, Wg_att, Wc_att, Wq_s,
                                                      v_att, v_s, Wa, Wg1, Wc1, Wg2, Wc2,
                                                      bg1, bc1, bg2, bc2, inp_mask, out_alpha);
    k_omel <<<dim3(400),  dim3(256), 0, stream>>>(y2g, Wo, bo, out_mel);
    k_spec <<<dim3(2000), dim3(256), 0, stream>>>(out_mel, Wspec, bspec, out_spec);
}